// Round 2
// baseline (7824.929 us; speedup 1.0000x reference)
//
#include <hip/hip_runtime.h>
#include <math.h>
#include <stdint.h>

// Problem: x[64][512][512] fp32, W[1024][2048] fp32, b[2048] fp32 -> out[64][512][512]
// z = [h,x]@W + b ; f,i,o,cb = split(z,4); c' = sig(f)*c + sig(i)*cb ; h' = sig(o)*c'
#define Bz 64
#define Tz 512
#define Dz 512
#define Hz 512

// ===================== shared helpers =====================
// storage col n = cg*8 + g*2 + j  <->  original W col = g*512 + 2*cg + j
__device__ __forceinline__ int col_of_n(int n) {
    int cc = n & 7;
    int cg = n >> 3;
    return (cc >> 1) * 512 + cg * 2 + (cc & 1);
}

// ===================== NEW PATH =====================
// ws layout:
//   Zx    : float [32768 m][2048 n]   (256 MB)  m = t*64+s, n gate-permuted
//   ghb   : float [2][64][512]        (256 KB)  double-buffered h
//   arrive: int   [512]               (2 KB)    per-step barrier counters
#define ZX_FLOATS  ((size_t)32768 * 2048)
#define GHB_FLOATS (2 * 64 * 512)
#define ARR_INTS   512
#define NEW_WS_BYTES (ZX_FLOATS * 4 + (size_t)GHB_FLOATS * 4 + (size_t)ARR_INTS * 4)

// persistent-kernel LDS layout (floats)
#define HS_STRIDE 516
#define WT_OFF    33024   /* 64*516 */
#define ZSC_OFF   37152   /* +8*516 */
#define ZRED_OFF  39232   /* +4*520 */
#define LDS_FLOATS 39752  /* +520 */
#define LDS_BYTES (LDS_FLOATS * 4)

__global__ __launch_bounds__(256) void zero_init(int* __restrict__ p, int n) {
    int i = blockIdx.x * 256 + threadIdx.x;
    if (i < n) p[i] = 0;
}

// --- Zx = x @ Wx (gate-permuted cols) + b : M=32768, N=2048, K=512 ---
__global__ __launch_bounds__(256) void zx_gemm(const float* __restrict__ x,
                                               const float* __restrict__ W,
                                               const float* __restrict__ bias,
                                               float* __restrict__ Zx) {
    __shared__ float As[16][132];   // As[k][r] (transposed stage)
    __shared__ float Bs[16][132];   // Bs[k][n_local]
    const int mb = blockIdx.x;      // 0..255 (2 timesteps x 64 batch rows)
    const int nb = blockIdx.y;      // 0..15
    const int tid = threadIdx.x;
    const int tx = tid & 15, ty = tid >> 4;

    float acc[8][8];
#pragma unroll
    for (int i = 0; i < 8; ++i)
#pragma unroll
        for (int j = 0; j < 8; ++j) acc[i][j] = 0.f;

    const int n_local = tid & 127;
    const int kp = tid >> 7;                       // 0..1
    const int cB = col_of_n(nb * 128 + n_local);   // fixed gather col for B stage

    for (int k0 = 0; k0 < 512; k0 += 16) {
        // stage A: rows m = mb*128 + r  ->  t = 2*mb + (r>>6), s = r&63
#pragma unroll
        for (int it = 0; it < 2; ++it) {
            int fi = it * 256 + tid;              // 0..511 float4s
            int r = fi >> 2, k4 = (fi & 3) * 4;
            int t = mb * 2 + (r >> 6), s = r & 63;
            float4 v = *(const float4*)(x + (size_t)s * (Tz * Dz) + (size_t)t * Dz + k0 + k4);
            As[k4 + 0][r] = v.x;
            As[k4 + 1][r] = v.y;
            As[k4 + 2][r] = v.z;
            As[k4 + 3][r] = v.w;
        }
        // stage B: gather from W rows 512..1023 (rows stay L2-hot across nb)
        {
            const float* wp = W + (size_t)(512 + k0 + kp * 8) * 2048 + cB;
#pragma unroll
            for (int ii = 0; ii < 8; ++ii)
                Bs[kp * 8 + ii][n_local] = wp[(size_t)ii * 2048];
        }
        __syncthreads();
#pragma unroll
        for (int k = 0; k < 16; ++k) {
            float a[8], b[8];
            *(float4*)(a)     = *(const float4*)&As[k][ty * 8];
            *(float4*)(a + 4) = *(const float4*)&As[k][ty * 8 + 4];
            *(float4*)(b)     = *(const float4*)&Bs[k][tx * 8];
            *(float4*)(b + 4) = *(const float4*)&Bs[k][tx * 8 + 4];
#pragma unroll
            for (int i = 0; i < 8; ++i)
#pragma unroll
                for (int j = 0; j < 8; ++j) acc[i][j] = fmaf(a[i], b[j], acc[i][j]);
        }
        __syncthreads();
    }
    // epilogue: + bias, store contiguous
#pragma unroll
    for (int i = 0; i < 8; ++i) {
        size_t m = (size_t)mb * 128 + ty * 8 + i;
        float* zp = Zx + m * 2048 + nb * 128 + tx * 8;
        float4 v0, v1;
        int nbase = nb * 128 + tx * 8;
        v0.x = acc[i][0] + bias[col_of_n(nbase + 0)];
        v0.y = acc[i][1] + bias[col_of_n(nbase + 1)];
        v0.z = acc[i][2] + bias[col_of_n(nbase + 2)];
        v0.w = acc[i][3] + bias[col_of_n(nbase + 3)];
        v1.x = acc[i][4] + bias[col_of_n(nbase + 4)];
        v1.y = acc[i][5] + bias[col_of_n(nbase + 5)];
        v1.z = acc[i][6] + bias[col_of_n(nbase + 6)];
        v1.w = acc[i][7] + bias[col_of_n(nbase + 7)];
        *(float4*)(zp) = v0;
        *(float4*)(zp + 4) = v1;
    }
}

__device__ __forceinline__ void gload_lds16(const float* g, float* l) {
    __builtin_amdgcn_global_load_lds((const __attribute__((address_space(1))) void*)g,
                                     (__attribute__((address_space(3))) void*)l,
                                     16, 0, 0);
}

// --- persistent recurrent kernel: 256 blocks (1/CU) x 512 threads ---
// block bx owns h-cols {2bx, 2bx+1} x 4 gates (8 z-cols); Wh slice resident in LDS.
// MUST be launched via hipLaunchCooperativeKernel (grid-wide spin barrier inside).
__global__ void __launch_bounds__(512) lstm_persist(const float* __restrict__ W,
                                                    const float* __restrict__ Zx,
                                                    float* __restrict__ ghb,
                                                    int* __restrict__ arrive,
                                                    float* __restrict__ out) {
    extern __shared__ float lds[];
    float* hs   = lds;              // [64][516] staged h_t
    float* wt   = lds + WT_OFF;     // [8][516]  Wh slice (resident)
    float* zsc  = lds + ZSC_OFF;    // [4][520]  K-split partials
    float* zred = lds + ZRED_OFF;   // [520]

    const int bx  = blockIdx.x;     // 0..255
    const int tid = threadIdx.x;
    const int lane = tid & 63;
    const int wid  = tid >> 6;      // 8 waves

    // load Wh slice once: wt[cc][k] = W[k][col(bx*8+cc)], k<512 (h-rows of W)
    for (int i = tid; i < 8 * 512; i += 512) {
        int cc = i >> 9, k = i & 511;
        wt[cc * HS_STRIDE + k] = W[(size_t)k * 2048 + col_of_n(bx * 8 + cc)];
    }
    float c_reg = 0.0f;             // persistent cell state (tid<128: (s,j) owner)
    __syncthreads();

    // GEMM thread decomposition: cp = c-pair, sp -> rows {sp, sp+32}, kq = K/4 split
    const int cp = tid & 3;
    const int sp = (tid >> 2) & 31;
    const int kq = tid >> 7;

    const float* ap0 = hs + sp * HS_STRIDE + kq * 128;
    const float* ap1 = hs + (sp + 32) * HS_STRIDE + kq * 128;
    const float* wp0 = wt + (cp * 2) * HS_STRIDE + kq * 128;
    const float* wp1 = wt + (cp * 2 + 1) * HS_STRIDE + kq * 128;

    for (int t = 0; t < Tz; ++t) {
        // ---- stage h_t -> LDS via global_load_lds (wave w: rows 8w..8w+7) ----
        const float* hsrc = ghb + (size_t)(t & 1) * (64 * 512);
#pragma unroll
        for (int r8 = 0; r8 < 8; ++r8) {
            int row = wid * 8 + r8;
#pragma unroll
            for (int half = 0; half < 2; ++half) {
                gload_lds16(hsrc + row * 512 + half * 256 + lane * 4,
                            hs + row * HS_STRIDE + half * 256);
            }
        }
        // prefetch my Zx cell (cell = tid = s*8 + cc)
        float zx_reg = Zx[((size_t)t * 64 + (tid >> 3)) * 2048 + bx * 8 + (tid & 7)];
        __syncthreads();   // drains vmcnt: h staged

        // ---- partial GEMM: 2 rows x 2 cols x 128 K ----
        float a00 = 0.f, a01 = 0.f, a10 = 0.f, a11 = 0.f;
#pragma unroll 4
        for (int kk = 0; kk < 128; kk += 4) {
            float4 av0 = *(const float4*)(ap0 + kk);
            float4 av1 = *(const float4*)(ap1 + kk);
            float4 wv0 = *(const float4*)(wp0 + kk);
            float4 wv1 = *(const float4*)(wp1 + kk);
            a00 += av0.x * wv0.x + av0.y * wv0.y + av0.z * wv0.z + av0.w * wv0.w;
            a01 += av0.x * wv1.x + av0.y * wv1.y + av0.z * wv1.z + av0.w * wv1.w;
            a10 += av1.x * wv0.x + av1.y * wv0.y + av1.z * wv0.z + av1.w * wv0.w;
            a11 += av1.x * wv1.x + av1.y * wv1.y + av1.z * wv1.z + av1.w * wv1.w;
        }
        *(float2*)(zsc + kq * 520 + sp * 8 + cp * 2)        = make_float2(a00, a01);
        *(float2*)(zsc + kq * 520 + (sp + 32) * 8 + cp * 2) = make_float2(a10, a11);
        __syncthreads();

        // ---- K-reduce + Zx (bias folded) ----
        zred[tid] = zsc[tid] + zsc[520 + tid] + zsc[2 * 520 + tid] + zsc[3 * 520 + tid] + zx_reg;
        __syncthreads();

        // ---- gates (tid<128 owns (s,j)); c-state stays in register ----
        if (tid < 128) {
            int s = tid >> 1, j = tid & 1;
            float zf = zred[s * 8 + 0 + j];
            float zi = zred[s * 8 + 2 + j];
            float zo = zred[s * 8 + 4 + j];
            float zc = zred[s * 8 + 6 + j];
            float sf = 1.f / (1.f + expf(-zf));
            float si = 1.f / (1.f + expf(-zi));
            float so = 1.f / (1.f + expf(-zo));
            float cnew = sf * c_reg + si * zc;
            c_reg = cnew;
            float h = so * cnew;
            int hc = bx * 2 + j;
            ghb[(size_t)((t + 1) & 1) * (64 * 512) + s * 512 + hc] = h;
            out[(size_t)s * (Tz * Hz) + (size_t)t * Hz + hc] = h;
        }
        __syncthreads();

        // ---- device-wide step barrier (per-t counter; BOUNDED spin) ----
        if (tid == 0) {
            __threadfence();                 // release: h visible device-wide
            atomicAdd(&arrive[t], 1);
            int iters = 0;
            while (__hip_atomic_load(&arrive[t], __ATOMIC_RELAXED,
                                     __HIP_MEMORY_SCOPE_AGENT) < 256) {
                __builtin_amdgcn_s_sleep(2);
                if (++iters >= 100000) break;   // safety: wrong-results > hang
            }
            __threadfence();                 // acquire: invalidate stale h lines
        }
        __syncthreads();
    }
}

// ===================== LEGACY PATH (verified fallback, 7560 us) =====================
#define WB_FLOATS   (64*1024*32)
#define HBUF_FLOATS (64*512)

__global__ __launch_bounds__(256) void zero_ws(float* __restrict__ p, int n) {
    int i = blockIdx.x * 256 + threadIdx.x;
    if (i < n) p[i] = 0.0f;
}

__global__ __launch_bounds__(256) void prep_w(const float* __restrict__ W,
                                              float* __restrict__ Wb) {
    int k = blockIdx.x;
    for (int it = 0; it < 8; ++it) {
        int col = it * 256 + threadIdx.x;
        float v = W[(size_t)k * 2048 + col];
        int g = col >> 9, rem = col & 511;
        int cg = rem >> 3, hc = rem & 7;
        int c = g * 8 + hc;
        Wb[((size_t)cg * 1024 + k) * 32 + c] = v;
    }
}

__global__ __launch_bounds__(256) void lstm_step(
    const float* __restrict__ x, const float* __restrict__ bias,
    const float* __restrict__ Wb, const float* __restrict__ hbr,
    float* __restrict__ hbw, float* __restrict__ cbuf,
    float* __restrict__ out, int t)
{
    const int cg  = blockIdx.x;
    const int sg  = blockIdx.y;
    const int tid = threadIdx.x;

    __shared__ float As[16 * 1028];
    __shared__ float zpart[8 * 512];
    __shared__ float zred[512];

    for (int it = 0; it < 16; ++it) {
        int fi = it * 256 + tid;
        int s  = fi >> 8;
        int k  = (fi & 255) * 4;
        const float* src;
        if (k < 512) src = hbr + (sg * 16 + s) * 512 + k;
        else         src = x + (size_t)(sg * 16 + s) * Tz * Dz + (size_t)t * Dz + (k - 512);
        float4 v = *(const float4*)src;
        *(float4*)(As + s * 1028 + k) = v;
    }
    __syncthreads();

    const int ct = tid & 7;
    const int st = (tid >> 3) & 3;
    const int kw = tid >> 5;

    float acc[4][4];
#pragma unroll
    for (int i = 0; i < 4; ++i)
#pragma unroll
        for (int j = 0; j < 4; ++j) acc[i][j] = 0.0f;

    const float* wp = Wb + (size_t)cg * 1024 * 32 + (size_t)(kw * 128) * 32 + ct * 4;
    const float* ap = As + st * 4 * 1028 + kw * 128;

#pragma unroll 4
    for (int kk = 0; kk < 128; kk += 4) {
        float4 w0 = *(const float4*)(wp + (kk + 0) * 32);
        float4 w1 = *(const float4*)(wp + (kk + 1) * 32);
        float4 w2 = *(const float4*)(wp + (kk + 2) * 32);
        float4 w3 = *(const float4*)(wp + (kk + 3) * 32);
        float4 a0 = *(const float4*)(ap + 0 * 1028 + kk);
        float4 a1 = *(const float4*)(ap + 1 * 1028 + kk);
        float4 a2 = *(const float4*)(ap + 2 * 1028 + kk);
        float4 a3 = *(const float4*)(ap + 3 * 1028 + kk);
#define FMA_ROW(i, ai)                                              \
        acc[i][0] += ai.x * w0.x + ai.y * w1.x + ai.z * w2.x + ai.w * w3.x; \
        acc[i][1] += ai.x * w0.y + ai.y * w1.y + ai.z * w2.y + ai.w * w3.y; \
        acc[i][2] += ai.x * w0.z + ai.y * w1.z + ai.z * w2.z + ai.w * w3.z; \
        acc[i][3] += ai.x * w0.w + ai.y * w1.w + ai.z * w2.w + ai.w * w3.w;
        FMA_ROW(0, a0)
        FMA_ROW(1, a1)
        FMA_ROW(2, a2)
        FMA_ROW(3, a3)
#undef FMA_ROW
    }

#pragma unroll
    for (int i = 0; i < 4; ++i) {
        float4 v = make_float4(acc[i][0], acc[i][1], acc[i][2], acc[i][3]);
        *(float4*)(zpart + kw * 512 + (st * 4 + i) * 32 + ct * 4) = v;
    }
    __syncthreads();

    {
        int o = tid * 2;
        float z0 = 0.0f, z1 = 0.0f;
#pragma unroll
        for (int w = 0; w < 8; ++w) {
            float2 v = *(const float2*)(zpart + w * 512 + o);
            z0 += v.x; z1 += v.y;
        }
        *(float2*)(zred + o) = make_float2(z0, z1);
    }
    __syncthreads();

    if (tid < 128) {
        int s  = tid >> 3;
        int hc = tid & 7;
        int colb = cg * 8 + hc;
        float zf = zred[s * 32 + hc]       + bias[colb];
        float zi = zred[s * 32 + 8 + hc]   + bias[512 + colb];
        float zo = zred[s * 32 + 16 + hc]  + bias[1024 + colb];
        float zc = zred[s * 32 + 24 + hc]  + bias[1536 + colb];

        int cidx = (sg * 64 + cg) * 128 + tid;
        float cold = cbuf[cidx];
        float sf = 1.0f / (1.0f + expf(-zf));
        float si = 1.0f / (1.0f + expf(-zi));
        float so = 1.0f / (1.0f + expf(-zo));
        float cnew = sf * cold + si * zc;
        float h = so * cnew;
        cbuf[cidx] = cnew;

        hbw[(sg * 16 + s) * 512 + colb] = h;
        out[(size_t)(sg * 16 + s) * Tz * Hz + (size_t)t * Hz + colb] = h;
    }
}

// ===================== launcher =====================
static void run_legacy(const float* x, const float* W, const float* bias,
                       float* out, void* d_ws, hipStream_t stream) {
    char* ws = (char*)d_ws;
    float* Wb   = (float*)ws;
    float* hbuf = (float*)(ws + (size_t)WB_FLOATS * 4);
    float* cbuf = hbuf + 2 * HBUF_FLOATS;

    zero_ws<<<384, 256, 0, stream>>>(hbuf, 98304);
    prep_w<<<1024, 256, 0, stream>>>(W, Wb);

    for (int t = 0; t < Tz; ++t) {
        float* hr = hbuf + (t & 1) * HBUF_FLOATS;
        float* hw = hbuf + ((t + 1) & 1) * HBUF_FLOATS;
        lstm_step<<<dim3(64, 4), 256, 0, stream>>>(x, bias, Wb, hr, hw, cbuf, out, t);
    }
}

extern "C" void kernel_launch(void* const* d_in, const int* in_sizes, int n_in,
                              void* d_out, int out_size, void* d_ws, size_t ws_size,
                              hipStream_t stream) {
    const float* x    = (const float*)d_in[0];
    const float* W    = (const float*)d_in[1];
    const float* bias = (const float*)d_in[2];
    float* out = (float*)d_out;

    // ---- one-time capability check (all host-side queries; capture-safe) ----
    static int mode = -1;   // 1 = cooperative persistent path, 0 = legacy
    if (mode < 0) {
        int ok = (ws_size >= NEW_WS_BYTES);
        if (ok) {
            int dev = 0;
            if (hipGetDevice(&dev) != hipSuccess) ok = 0;
            int coop = 0, ncu = 0;
            if (ok) {
                hipDeviceGetAttribute(&coop, hipDeviceAttributeCooperativeLaunch, dev);
                hipDeviceGetAttribute(&ncu, hipDeviceAttributeMultiprocessorCount, dev);
                if (!coop || ncu < 256) ok = 0;
            }
            if (ok && hipFuncSetAttribute((const void*)lstm_persist,
                        hipFuncAttributeMaxDynamicSharedMemorySize,
                        (int)LDS_BYTES) != hipSuccess) ok = 0;
            if (ok) {
                int nblk = 0;
                if (hipOccupancyMaxActiveBlocksPerMultiprocessor(&nblk,
                        lstm_persist, 512, LDS_BYTES) != hipSuccess || nblk < 1)
                    ok = 0;
            }
        }
        mode = ok ? 1 : 0;
    }

    if (mode == 1) {
        float* Zx   = (float*)d_ws;
        float* ghb  = Zx + ZX_FLOATS;
        int* arrive = (int*)(ghb + GHB_FLOATS);

        zero_init<<<dim3((GHB_FLOATS + ARR_INTS + 255) / 256), 256, 0, stream>>>(
            (int*)ghb, GHB_FLOATS + ARR_INTS);
        zx_gemm<<<dim3(256, 16), 256, 0, stream>>>(x, W, bias, Zx);

        const float* Wp = W; const float* Zxp = Zx;
        float* ghbp = ghb; int* arrp = arrive; float* outp = out;
        void* args[] = {(void*)&Wp, (void*)&Zxp, (void*)&ghbp, (void*)&arrp, (void*)&outp};
        hipError_t e = hipLaunchCooperativeKernel((const void*)lstm_persist,
                                                  dim3(256), dim3(512),
                                                  args, (unsigned)LDS_BYTES, stream);
        if (e == hipSuccess) return;
        mode = 0;   // cooperative launch rejected -> verified legacy path
    }

    run_legacy(x, W, bias, out, d_ws, stream);
}